// Round 7
// baseline (73.137 us; speedup 1.0000x reference)
//
#include <hip/hip_runtime.h>
#include <math.h>

// EGNN forward, N=1024, DIM=3, DEPTH=2, F=64, L=1.0, RC=0.5
//
// R7: launch-overhead-bound (R6: ~20us exec + ~50us in 7 launch gaps).
// Fused to 3 kernels along block-index alignment (everything consuming a
// per-node quantity lives in the block that produced it):
//   A = prep0 + pair0 + node0   (1024 blocks; depth-0 constants recomputed
//       per block by wave 0 -- weight-only, ~300 fma, free in parallel)
//   B = depth-1 prep: cooperative mean(h1) (no atomics -> no memset),
//       per-node HiE/Hj/P/U/V, aux (Hm/b0/b1)
//   C = pair1 + node1 + final -> writes out directly
// Math identical to R6 (moment expansion, coord-MLP linearization).

#define NN 1024
#define FF 64
#define RA 0.57735027f      // r-node spacing; u = r/RA in [0,3]
#define INV_RA 1.7320508f

__device__ __forceinline__ float silu_exact(float z) {
  return z / (1.0f + __expf(-z));
}
__device__ __forceinline__ float silu_deriv(float z) {
  float s = 1.0f / (1.0f + __expf(-z));
  return s * (1.0f + z * (1.0f - s));
}
__device__ __forceinline__ float wred(float v) {
  v += __shfl_xor(v, 1);  v += __shfl_xor(v, 2);  v += __shfl_xor(v, 4);
  v += __shfl_xor(v, 8);  v += __shfl_xor(v, 16); v += __shfl_xor(v, 32);
  return v;
}

// geometry for one (i,j) pair: r (periodic feature norm), p (min-image), swc
__device__ __forceinline__ void pair_geom(float xi0, float xi1, float xi2,
                                          const float* __restrict__ x, int j, int i,
                                          float& r, float& p0, float& p1, float& p2,
                                          float& swc) {
  float d0 = xi0 - x[j * 3 + 0];
  float d1 = xi1 - x[j * 3 + 1];
  float d2 = xi2 - x[j * 3 + 2];
  float s0 = __builtin_amdgcn_sinf(0.5f * d0);   // sin(pi d) = v_sin(d/2 rev)
  float s1 = __builtin_amdgcn_sinf(0.5f * d1);
  float s2 = __builtin_amdgcn_sinf(0.5f * d2);
  r = __builtin_amdgcn_sqrtf(fmaf(s0, s0, fmaf(s1, s1, s2 * s2)));
  p0 = d0 - rintf(d0);
  p1 = d1 - rintf(d1);
  p2 = d2 - rintf(d2);
  float rij = __builtin_amdgcn_sqrtf(fmaf(p0, p0, fmaf(p1, p1, p2 * p2)));
  float cosv = __builtin_amdgcn_cosf(2.0f * (rij - 0.25f));
  float sw = (rij < 0.25f) ? 1.0f
           : ((rij < 0.5f) ? fmaf(0.5f, cosv, 0.5f) : 0.0f);
  swc = (j == i) ? 0.0f : sw * (1.0f / 1023.0f);
}

// silu 4-node poly coeffs in u basis (nodes u=0..3, spacing RA in r)
__device__ __forceinline__ float4 acoef(float c, float wk) {
  float g0 = silu_exact(c);
  float g1 = silu_exact(fmaf(RA, wk, c));
  float g2 = silu_exact(fmaf(2.0f * RA, wk, c));
  float g3 = silu_exact(fmaf(3.0f * RA, wk, c));
  float d1 = g1 - g0;
  float d2 = g2 - 2.0f * g1 + g0;
  float d3 = g3 - 3.0f * g2 + 3.0f * g1 - g0;
  return make_float4(g0,
                     d1 - 0.5f * d2 + (1.0f / 3.0f) * d3,
                     0.5f * (d2 - d3),
                     (1.0f / 6.0f) * d3);
}

// =================== A: prep0 + pair0 + node0 ===================
__global__ __launch_bounds__(256) void k_d0(const float* __restrict__ x_in,
                                            const float* __restrict__ ew1,   // d0 (129,64)
                                            const float* __restrict__ ew2,
                                            const float* __restrict__ cw1,
                                            const float* __restrict__ eb1,
                                            const float* __restrict__ eb2,
                                            const float* __restrict__ cb1,
                                            const float* __restrict__ cw2,
                                            const float* __restrict__ cb2p,
                                            const float* __restrict__ nw1,
                                            const float* __restrict__ nb1,
                                            const float* __restrict__ nw2,
                                            const float* __restrict__ nb2,
                                            float* __restrict__ xB,
                                            float* __restrict__ h1) {
  __shared__ float gS[FF], tS[FF];
  __shared__ float acS[FF * 4];
  __shared__ float P4S[4];
  __shared__ float redS[4][8];
  __shared__ float QS[3], X2S[3];
  __shared__ float sS[FF], mS[FF], hidS[FF];
  __shared__ float c0pS;

  const int i = blockIdx.x;
  const int tid = threadIdx.x;
  const int lane = tid & 63;
  const int w = tid >> 6;

  // ---- wave0: depth-0 constants (weight-only) ----
  if (tid < 64) {
    const int k = tid;
    float colA = 0.f, colB = 0.f;
    #pragma unroll 4
    for (int m = 0; m < FF; ++m) {
      colA += ew1[m * FF + k];
      colB += ew1[(FF + m) * FF + k];
    }
    const float wk = ew1[128 * FF + k];
    const float c0 = colA + eb1[k] + colB;
    float4 a = acoef(c0, wk);
    *(float4*)&acS[k * 4] = a;

    float cbp = cb1[k];
    #pragma unroll 4
    for (int m = 0; m < FF; ++m) cbp += eb2[m] * cw1[m * FF + k];
    float sig = 1.0f / (1.0f + __expf(-cbp));
    float dsilu = sig * (1.0f + cbp * (1.0f - sig));
    float cw2k = cw2[k];
    gS[k] = dsilu * cw2k;
    float c0p = wred(cbp * sig * cw2k);
    if (k == 0) c0pS = c0p;
  }
  __syncthreads();
  if (tid < 64) {
    float t = 0.f;
    #pragma unroll 4
    for (int m = 0; m < FF; ++m) t += cw1[tid * FF + m] * gS[m];
    tS[tid] = t;
  }
  __syncthreads();
  if (tid < 64) {
    const int k = tid;
    float cc = 0.f;
    #pragma unroll 4
    for (int m = 0; m < FF; ++m) cc += ew2[k * FF + m] * tS[m];
    float4 a = *(const float4*)&acS[k * 4];
    float P0 = wred(cc * a.x);
    float P1 = wred(cc * a.y);
    float P2 = wred(cc * a.z);
    float P3 = wred(cc * a.w);
    if (k == 0) {
      float W0 = c0pS + *cb2p;
      P4S[0] = P0 + W0; P4S[1] = P1; P4S[2] = P2; P4S[3] = P3;
    }
  }
  __syncthreads();

  // ---- pair loop (all 256 threads) ----
  const float xi0 = x_in[i * 3 + 0], xi1 = x_in[i * 3 + 1], xi2 = x_in[i * 3 + 2];
  const float4 P4 = make_float4(P4S[0], P4S[1], P4S[2], P4S[3]);

  float Q1 = 0.f, Q2 = 0.f, Q3 = 0.f, dx0 = 0.f, dx1 = 0.f, dx2 = 0.f;
  #pragma unroll
  for (int t = 0; t < 4; ++t) {
    const int j = t * 256 + tid;
    float r, p0, p1, p2, swc;
    pair_geom(xi0, xi1, xi2, x_in, j, i, r, p0, p1, p2, swc);
    float u = r * INV_RA;
    float u2 = u * u;
    Q1 += u; Q2 += u2; Q3 += u2 * u;
    float wj = fmaf(fmaf(fmaf(P4.w, u, P4.z), u, P4.y), u, P4.x);
    float wv = wj * swc;
    dx0 = fmaf(wv, p0, dx0);
    dx1 = fmaf(wv, p1, dx1);
    dx2 = fmaf(wv, p2, dx2);
  }
  Q1 = wred(Q1); Q2 = wred(Q2); Q3 = wred(Q3);
  dx0 = wred(dx0); dx1 = wred(dx1); dx2 = wred(dx2);
  if (lane == 0) {
    redS[w][0] = Q1; redS[w][1] = Q2; redS[w][2] = Q3;
    redS[w][3] = dx0; redS[w][4] = dx1; redS[w][5] = dx2;
  }
  __syncthreads();
  if (tid == 0) {
    float q1 = 0, q2 = 0, q3 = 0, e0 = 0, e1 = 0, e2 = 0;
    #pragma unroll
    for (int ww = 0; ww < 4; ++ww) {
      q1 += redS[ww][0]; q2 += redS[ww][1]; q3 += redS[ww][2];
      e0 += redS[ww][3]; e1 += redS[ww][4]; e2 += redS[ww][5];
    }
    QS[0] = q1; QS[1] = q2; QS[2] = q3;
    float x20 = xi0 + e0, x21 = xi1 + e1, x22 = xi2 + e2;
    xB[i * 3 + 0] = x20; xB[i * 3 + 1] = x21; xB[i * 3 + 2] = x22;
  }
  __syncthreads();

  // ---- node0 tail (threads 0..63) ----
  if (tid < 64) {
    const int f = tid;
    float4 a = *(const float4*)&acS[f * 4];
    float s = 1023.0f * a.x;
    s = fmaf(a.y, QS[0], s);
    s = fmaf(a.z, QS[1], s);
    s = fmaf(a.w, QS[2], s);
    sS[f] = s;
  }
  __syncthreads();
  if (tid < 64) {
    const int f = tid;
    float m = 1023.0f * eb2[f];
    #pragma unroll 4
    for (int k = 0; k < FF; ++k) m += sS[k] * ew2[k * FF + f];
    mS[f] = m;
  }
  __syncthreads();
  if (tid < 64) {
    const int f = tid;
    float z = nb1[f];
    #pragma unroll 4
    for (int k = 0; k < FF; ++k) z += nw1[k * FF + f];            // h == 1 part
    #pragma unroll 4
    for (int k = 0; k < FF; ++k) z += mS[k] * nw1[(FF + k) * FF + f];
    hidS[f] = silu_exact(z);
  }
  __syncthreads();
  if (tid < 64) {
    const int f = tid;
    float o = nb2[f] + 1.0f;
    #pragma unroll 4
    for (int k = 0; k < FF; ++k) o += hidS[k] * nw2[k * FF + f];
    h1[i * FF + f] = o;
  }
}

// =================== B: depth-1 prep ===================
// grid = 64 blocks x 256; block handles 16 nodes (wave w: 4 nodes)
__global__ __launch_bounds__(256) void k_prep1(const float* __restrict__ h1,
                                               const float* __restrict__ ew1,   // d1 (129,64)
                                               const float* __restrict__ ew2,
                                               const float* __restrict__ cw1,
                                               const float* __restrict__ eb1,
                                               const float* __restrict__ eb2,
                                               const float* __restrict__ cb1,
                                               const float* __restrict__ cw2,
                                               const float* __restrict__ cb2p,
                                               float* __restrict__ HiE,
                                               float* __restrict__ Hj,
                                               float* __restrict__ P,     // (N,4)
                                               float* __restrict__ U,
                                               float* __restrict__ V,
                                               float* __restrict__ aux) { // 192: Hm,b0,b1
  __shared__ float partS[256];
  __shared__ float hmeanS[FF], HmS[FF], b0S[FF], b1S[FF], ccS[FF], gS[FF], tS[FF];
  __shared__ float W0S;

  const int tid = threadIdx.x;
  const int lane = tid & 63;
  const int w = tid >> 6;

  // ---- cooperative mean(h1) ----
  {
    const int k = tid & 63;
    const int i0 = (tid >> 6) * 256;
    float p = 0.f;
    #pragma unroll 4
    for (int ii = 0; ii < 256; ++ii) p += h1[(i0 + ii) * FF + k];
    partS[tid] = p;
  }
  __syncthreads();
  if (tid < 64)
    hmeanS[tid] = (partS[tid] + partS[64 + tid] + partS[128 + tid] + partS[192 + tid])
                  * (1.0f / 1024.0f);
  __syncthreads();

  // ---- means, B-fit, ccw phase 1 ----
  if (tid < 64) {
    const int k = tid;
    float Hm = 0.f, HiEm = eb1[k];
    #pragma unroll 4
    for (int m = 0; m < FF; ++m) {
      float hv = hmeanS[m];
      HiEm += hv * ew1[m * FF + k];
      Hm += hv * ew1[(FF + m) * FF + k];
    }
    HmS[k] = Hm;
    const float cbar = HiEm + Hm;
    const float wk = ew1[128 * FF + k];
    float sp_lo = silu_deriv(fmaf(0.4f, wk, cbar));
    float sp_hi = silu_deriv(fmaf(1.3f, wk, cbar));
    float b1 = (sp_hi - sp_lo) * (1.0f / 0.9f);
    b0S[k] = fmaf(-0.4f, b1, sp_lo);
    b1S[k] = b1;

    float cbp = cb1[k];
    #pragma unroll 4
    for (int m = 0; m < FF; ++m) cbp += eb2[m] * cw1[m * FF + k];
    float sig = 1.0f / (1.0f + __expf(-cbp));
    float dsilu = sig * (1.0f + cbp * (1.0f - sig));
    float cw2k = cw2[k];
    gS[k] = dsilu * cw2k;
    float c0p = wred(cbp * sig * cw2k);
    if (k == 0) W0S = c0p + *cb2p;
  }
  __syncthreads();
  if (tid < 64) {
    float t = 0.f;
    #pragma unroll 4
    for (int m = 0; m < FF; ++m) t += cw1[tid * FF + m] * gS[m];
    tS[tid] = t;
  }
  __syncthreads();
  if (tid < 64) {
    float cc = 0.f;
    #pragma unroll 4
    for (int m = 0; m < FF; ++m) cc += ew2[tid * FF + m] * tS[m];
    ccS[tid] = cc;
  }
  __syncthreads();

  // ---- per-node: HiE/Hj/P/U/V ----
  const float Hm = HmS[lane], b0 = b0S[lane], b1 = b1S[lane], cc = ccS[lane];
  const float wk = ew1[128 * FF + lane];
  #pragma unroll
  for (int nn = 0; nn < 4; ++nn) {
    const int v = blockIdx.x * 16 + w * 4 + nn;
    float a = eb1[lane], b = 0.f;
    #pragma unroll 4
    for (int m = 0; m < FF; ++m) {
      float hv = h1[v * FF + m];
      a += hv * ew1[m * FF + lane];
      b += hv * ew1[(FF + m) * FF + lane];
    }
    HiE[v * FF + lane] = a;
    Hj[v * FF + lane] = b;
    float4 ac = acoef(a + Hm, wk);
    float delta = b - Hm;
    float P0 = wred(cc * ac.x);
    float P1 = wred(cc * ac.y);
    float P2 = wred(cc * ac.z);
    float P3 = wred(cc * ac.w);
    float Uv = wred(cc * b0 * delta);
    float Vv = wred(cc * b1 * delta);
    if (lane == 0) {
      *(float4*)&P[v * 4] = make_float4(P0 + W0S, P1, P2, P3);
      U[v] = Uv;
      V[v] = Vv;
    }
  }
  if (blockIdx.x == 0 && tid < 64) {
    aux[tid] = HmS[tid];
    aux[64 + tid] = b0S[tid];
    aux[128 + tid] = b1S[tid];
  }
}

// =================== C: pair1 + node1 + final ===================
__global__ __launch_bounds__(256) void k_d1(const float* __restrict__ xB,
                                            const float* __restrict__ h1,
                                            const float* __restrict__ HiE,
                                            const float* __restrict__ Hj,
                                            const float* __restrict__ P,
                                            const float* __restrict__ U,
                                            const float* __restrict__ V,
                                            const float* __restrict__ aux,
                                            const float* __restrict__ ew1,   // d1 (for w1r)
                                            const float* __restrict__ ew2,
                                            const float* __restrict__ eb2,
                                            const float* __restrict__ nw1,
                                            const float* __restrict__ nb1,
                                            const float* __restrict__ nw2,
                                            const float* __restrict__ nb2,
                                            const float* __restrict__ fw,    // (64,3)
                                            float* __restrict__ out) {
  __shared__ float redS[4][8];
  __shared__ float QS[3], X2S[3];
  __shared__ float sS[FF], mS[FF], hidS[FF], hvS[FF];

  const int i = blockIdx.x;
  const int tid = threadIdx.x;
  const int lane = tid & 63;
  const int w = tid >> 6;

  const float4 P4 = *(const float4*)&P[i * 4];
  const float xi0 = xB[i * 3 + 0], xi1 = xB[i * 3 + 1], xi2 = xB[i * 3 + 2];

  float Q1 = 0.f, Q2 = 0.f, Q3 = 0.f, dx0 = 0.f, dx1 = 0.f, dx2 = 0.f;
  #pragma unroll
  for (int t = 0; t < 4; ++t) {
    const int j = t * 256 + tid;
    float r, p0, p1, p2, swc;
    pair_geom(xi0, xi1, xi2, xB, j, i, r, p0, p1, p2, swc);
    float u = r * INV_RA;
    float u2 = u * u;
    Q1 += u; Q2 += u2; Q3 += u2 * u;
    float wj = fmaf(fmaf(fmaf(P4.w, u, P4.z), u, P4.y), u, P4.x);
    wj += fmaf(r, V[j], U[j]);
    float wv = wj * swc;
    dx0 = fmaf(wv, p0, dx0);
    dx1 = fmaf(wv, p1, dx1);
    dx2 = fmaf(wv, p2, dx2);
  }
  Q1 = wred(Q1); Q2 = wred(Q2); Q3 = wred(Q3);
  dx0 = wred(dx0); dx1 = wred(dx1); dx2 = wred(dx2);
  if (lane == 0) {
    redS[w][0] = Q1; redS[w][1] = Q2; redS[w][2] = Q3;
    redS[w][3] = dx0; redS[w][4] = dx1; redS[w][5] = dx2;
  }
  __syncthreads();
  if (tid == 0) {
    float q1 = 0, q2 = 0, q3 = 0, e0 = 0, e1 = 0, e2 = 0;
    #pragma unroll
    for (int ww = 0; ww < 4; ++ww) {
      q1 += redS[ww][0]; q2 += redS[ww][1]; q3 += redS[ww][2];
      e0 += redS[ww][3]; e1 += redS[ww][4]; e2 += redS[ww][5];
    }
    QS[0] = q1; QS[1] = q2; QS[2] = q3;
    X2S[0] = xi0 + e0; X2S[1] = xi1 + e1; X2S[2] = xi2 + e2;
  }
  __syncthreads();

  // ---- node1 tail ----
  if (tid < 64) {
    const int f = tid;
    const float Hm = aux[f], b0 = aux[64 + f];
    const float wk = ew1[128 * FF + f];
    float4 a = acoef(HiE[i * FF + f] + Hm, wk);
    float delta = Hj[i * FF + f] - Hm;
    float s = 1023.0f * a.x;
    s = fmaf(a.y, QS[0], s);
    s = fmaf(a.z, QS[1], s);
    s = fmaf(a.w, QS[2], s);
    s = fmaf(-b0, delta, s);
    sS[f] = s;
    hvS[f] = h1[i * FF + f];
  }
  __syncthreads();
  if (tid < 64) {
    const int f = tid;
    float m = 1023.0f * eb2[f];
    #pragma unroll 4
    for (int k = 0; k < FF; ++k) m += sS[k] * ew2[k * FF + f];
    mS[f] = m;
  }
  __syncthreads();
  if (tid < 64) {
    const int f = tid;
    float z = nb1[f];
    #pragma unroll 4
    for (int k = 0; k < FF; ++k) z += hvS[k] * nw1[k * FF + f];
    #pragma unroll 4
    for (int k = 0; k < FF; ++k) z += mS[k] * nw1[(FF + k) * FF + f];
    hidS[f] = silu_exact(z);
  }
  __syncthreads();
  if (tid < 64) {
    const int f = tid;
    float o = nb2[f] + hvS[f];
    #pragma unroll 4
    for (int k = 0; k < FF; ++k) o += hidS[k] * nw2[k * FF + f];
    float p0 = wred(o * fw[f * 3 + 0]);
    float p1 = wred(o * fw[f * 3 + 1]);
    float p2 = wred(o * fw[f * 3 + 2]);
    if (f == 0) {
      out[i * 3 + 0] = p0 + X2S[0];
      out[i * 3 + 1] = p1 + X2S[1];
      out[i * 3 + 2] = p2 + X2S[2];
    }
  }
}

extern "C" void kernel_launch(void* const* d_in, const int* in_sizes, int n_in,
                              void* d_out, int out_size, void* d_ws, size_t ws_size,
                              hipStream_t stream) {
  const float* x_in = (const float*)d_in[0];
  const float* ew1  = (const float*)d_in[1];   // (2,129,64)
  const float* eb1  = (const float*)d_in[2];   // (2,64)
  const float* ew2  = (const float*)d_in[3];   // (2,64,64)
  const float* eb2  = (const float*)d_in[4];   // (2,64)
  const float* cw1  = (const float*)d_in[5];   // (2,64,64)
  const float* cb1  = (const float*)d_in[6];   // (2,64)
  const float* cw2  = (const float*)d_in[7];   // (2,64,1)
  const float* cb2  = (const float*)d_in[8];   // (2,1)
  const float* nw1  = (const float*)d_in[9];   // (2,128,64)
  const float* nb1  = (const float*)d_in[10];  // (2,64)
  const float* nw2  = (const float*)d_in[11];  // (2,64,64)
  const float* nb2  = (const float*)d_in[12];  // (2,64)
  const float* fw   = (const float*)d_in[13];  // (64,3)
  float* out = (float*)d_out;

  float* ws = (float*)d_ws;
  float* xB  = ws;               // 3072
  float* h1  = xB + 3072;        // 65536
  float* HiE = h1 + 65536;       // 65536
  float* Hj  = HiE + 65536;      // 65536
  float* P   = Hj + 65536;       // 4096
  float* U   = P + 4096;         // 1024
  float* V   = U + 1024;         // 1024
  float* aux = V + 1024;         // 256 (192 used)

  const float* ew1d1 = ew1 + 129 * FF;

  k_d0<<<NN, 256, 0, stream>>>(x_in, ew1, ew2, cw1, eb1, eb2, cb1, cw2, cb2,
                               nw1, nb1, nw2, nb2, xB, h1);
  k_prep1<<<64, 256, 0, stream>>>(h1, ew1d1, ew2 + 4096, cw1 + 4096,
                                  eb1 + FF, eb2 + FF, cb1 + FF, cw2 + FF, cb2 + 1,
                                  HiE, Hj, P, U, V, aux);
  k_d1<<<NN, 256, 0, stream>>>(xB, h1, HiE, Hj, P, U, V, aux,
                               ew1d1, ew2 + 4096, eb2 + FF,
                               nw1 + 128 * FF, nb1 + FF, nw2 + 4096, nb2 + FF,
                               fw, out);
}

// Round 8
// 47.587 us; speedup vs baseline: 1.5369x; 1.5369x over previous
//
#include <hip/hip_runtime.h>
#include <math.h>

// EGNN forward, N=1024, DIM=3, DEPTH=2, F=64, L=1.0, RC=0.5
//
// R8: R7's k_prep1 was 50us (64 blocks, 1 wave/CU, serial scalar loads,
// VALUBusy 1.1%). Restructured:
//   - mean(h1): 256 blocks, coalesced float4 loads, shfl+LDS reduce (~2us)
//   - d1 coord-weight chain (cbp->g->t->cc->W0): weights-only, computed once
//     by k_d0 block0/wave1 via shfl matvecs, hidden under pair work -> ccD1
//   - per-node HiE/Hj: 1 node per wave, h1 row staged in LDS
//   - k_d0 d0-chain converted to shfl (3 barriers -> 1)
// Math identical to R6/R7 (moment expansion + coord-MLP linearization).

#define NN 1024
#define FF 64
#define RA 0.57735027f      // r-node spacing; u = r/RA in [0,3]
#define INV_RA 1.7320508f

__device__ __forceinline__ float silu_exact(float z) {
  return z / (1.0f + __expf(-z));
}
__device__ __forceinline__ float silu_deriv(float z) {
  float s = 1.0f / (1.0f + __expf(-z));
  return s * (1.0f + z * (1.0f - s));
}
__device__ __forceinline__ float wred(float v) {
  v += __shfl_xor(v, 1);  v += __shfl_xor(v, 2);  v += __shfl_xor(v, 4);
  v += __shfl_xor(v, 8);  v += __shfl_xor(v, 16); v += __shfl_xor(v, 32);
  return v;
}

__device__ __forceinline__ void pair_geom(float xi0, float xi1, float xi2,
                                          const float* __restrict__ x, int j, int i,
                                          float& r, float& p0, float& p1, float& p2,
                                          float& swc) {
  float d0 = xi0 - x[j * 3 + 0];
  float d1 = xi1 - x[j * 3 + 1];
  float d2 = xi2 - x[j * 3 + 2];
  float s0 = __builtin_amdgcn_sinf(0.5f * d0);   // sin(pi d) = v_sin(d/2 rev)
  float s1 = __builtin_amdgcn_sinf(0.5f * d1);
  float s2 = __builtin_amdgcn_sinf(0.5f * d2);
  r = __builtin_amdgcn_sqrtf(fmaf(s0, s0, fmaf(s1, s1, s2 * s2)));
  p0 = d0 - rintf(d0);
  p1 = d1 - rintf(d1);
  p2 = d2 - rintf(d2);
  float rij = __builtin_amdgcn_sqrtf(fmaf(p0, p0, fmaf(p1, p1, p2 * p2)));
  float cosv = __builtin_amdgcn_cosf(2.0f * (rij - 0.25f));
  float sw = (rij < 0.25f) ? 1.0f
           : ((rij < 0.5f) ? fmaf(0.5f, cosv, 0.5f) : 0.0f);
  swc = (j == i) ? 0.0f : sw * (1.0f / 1023.0f);
}

// silu 4-node poly coeffs in u basis (nodes u=0..3, spacing RA in r)
__device__ __forceinline__ float4 acoef(float c, float wk) {
  float g0 = silu_exact(c);
  float g1 = silu_exact(fmaf(RA, wk, c));
  float g2 = silu_exact(fmaf(2.0f * RA, wk, c));
  float g3 = silu_exact(fmaf(3.0f * RA, wk, c));
  float d1 = g1 - g0;
  float d2 = g2 - 2.0f * g1 + g0;
  float d3 = g3 - 3.0f * g2 + 3.0f * g1 - g0;
  return make_float4(g0,
                     d1 - 0.5f * d2 + (1.0f / 3.0f) * d3,
                     0.5f * (d2 - d3),
                     (1.0f / 6.0f) * d3);
}

// =================== A: prep0 + pair0 + node0 (+ d1 cc chain on blk0/w1) ===================
__global__ __launch_bounds__(256) void k_d0(const float* __restrict__ x_in,
                                            const float* __restrict__ ew1,   // d0 (129,64)
                                            const float* __restrict__ ew2,
                                            const float* __restrict__ cw1,
                                            const float* __restrict__ eb1,
                                            const float* __restrict__ eb2,
                                            const float* __restrict__ cb1,
                                            const float* __restrict__ cw2,
                                            const float* __restrict__ cb2p,
                                            const float* __restrict__ nw1,
                                            const float* __restrict__ nb1,
                                            const float* __restrict__ nw2,
                                            const float* __restrict__ nb2,
                                            const float* __restrict__ cw1d1,
                                            const float* __restrict__ ew2d1,
                                            const float* __restrict__ eb2d1,
                                            const float* __restrict__ cb1d1,
                                            const float* __restrict__ cw2d1,
                                            const float* __restrict__ cb2d1,
                                            float* __restrict__ xB,
                                            float* __restrict__ h1,
                                            float* __restrict__ ccD1) {  // 65
  __shared__ float acS[FF * 4];
  __shared__ float P4S[4];
  __shared__ float redS[4][8];
  __shared__ float QS[3];
  __shared__ float sS[FF], mS[FF], hidS[FF];

  const int i = blockIdx.x;
  const int tid = threadIdx.x;
  const int lane = tid & 63;
  const int w = tid >> 6;

  // ---- region 1 (barrier-free): wave0 = d0 constants; blk0/wave1 = d1 cc chain ----
  if (w == 0) {
    const int k = lane;
    float colA = 0.f, colB = 0.f;
    #pragma unroll 4
    for (int m = 0; m < FF; ++m) {
      colA += ew1[m * FF + k];
      colB += ew1[(FF + m) * FF + k];
    }
    const float wk = ew1[128 * FF + k];
    float4 a = acoef(colA + eb1[k] + colB, wk);
    *(float4*)&acS[k * 4] = a;

    float cbp = cb1[k];
    #pragma unroll 4
    for (int m = 0; m < FF; ++m) cbp = fmaf(eb2[m], cw1[m * FF + k], cbp);
    float sig = 1.0f / (1.0f + __expf(-cbp));
    float dsil = sig * (1.0f + cbp * (1.0f - sig));
    float cw2k = cw2[k];
    float g = dsil * cw2k;
    float c0p = wred(cbp * sig * cw2k);
    float t = 0.f;
    #pragma unroll 4
    for (int m = 0; m < FF; ++m) t = fmaf(cw1[k * FF + m], __shfl(g, m), t);
    float cc = 0.f;
    #pragma unroll 4
    for (int m = 0; m < FF; ++m) cc = fmaf(ew2[k * FF + m], __shfl(t, m), cc);
    float P0 = wred(cc * a.x);
    float P1 = wred(cc * a.y);
    float P2 = wred(cc * a.z);
    float P3 = wred(cc * a.w);
    if (k == 0) {
      float W0 = c0p + *cb2p;
      P4S[0] = P0 + W0; P4S[1] = P1; P4S[2] = P2; P4S[3] = P3;
    }
  } else if (w == 1 && i == 0) {
    // d1 coord-weight chain -> global ccD1 (weights-only, computed once)
    const int k = lane;
    float cbp = cb1d1[k];
    #pragma unroll 4
    for (int m = 0; m < FF; ++m) cbp = fmaf(eb2d1[m], cw1d1[m * FF + k], cbp);
    float sig = 1.0f / (1.0f + __expf(-cbp));
    float dsil = sig * (1.0f + cbp * (1.0f - sig));
    float cw2k = cw2d1[k];
    float g = dsil * cw2k;
    float c0p = wred(cbp * sig * cw2k);
    float t = 0.f;
    #pragma unroll 4
    for (int m = 0; m < FF; ++m) t = fmaf(cw1d1[k * FF + m], __shfl(g, m), t);
    float cc = 0.f;
    #pragma unroll 4
    for (int m = 0; m < FF; ++m) cc = fmaf(ew2d1[k * FF + m], __shfl(t, m), cc);
    ccD1[k] = cc;
    if (k == 0) ccD1[FF] = c0p + *cb2d1;   // W0 for depth 1
  }
  __syncthreads();

  // ---- pair loop (all 256 threads) ----
  const float xi0 = x_in[i * 3 + 0], xi1 = x_in[i * 3 + 1], xi2 = x_in[i * 3 + 2];
  const float4 P4 = make_float4(P4S[0], P4S[1], P4S[2], P4S[3]);

  float Q1 = 0.f, Q2 = 0.f, Q3 = 0.f, dx0 = 0.f, dx1 = 0.f, dx2 = 0.f;
  #pragma unroll
  for (int t = 0; t < 4; ++t) {
    const int j = t * 256 + tid;
    float r, p0, p1, p2, swc;
    pair_geom(xi0, xi1, xi2, x_in, j, i, r, p0, p1, p2, swc);
    float u = r * INV_RA;
    float u2 = u * u;
    Q1 += u; Q2 += u2; Q3 += u2 * u;
    float wj = fmaf(fmaf(fmaf(P4.w, u, P4.z), u, P4.y), u, P4.x);
    float wv = wj * swc;
    dx0 = fmaf(wv, p0, dx0);
    dx1 = fmaf(wv, p1, dx1);
    dx2 = fmaf(wv, p2, dx2);
  }
  Q1 = wred(Q1); Q2 = wred(Q2); Q3 = wred(Q3);
  dx0 = wred(dx0); dx1 = wred(dx1); dx2 = wred(dx2);
  if (lane == 0) {
    redS[w][0] = Q1; redS[w][1] = Q2; redS[w][2] = Q3;
    redS[w][3] = dx0; redS[w][4] = dx1; redS[w][5] = dx2;
  }
  __syncthreads();
  if (tid == 0) {
    float q1 = 0, q2 = 0, q3 = 0, e0 = 0, e1 = 0, e2 = 0;
    #pragma unroll
    for (int ww = 0; ww < 4; ++ww) {
      q1 += redS[ww][0]; q2 += redS[ww][1]; q3 += redS[ww][2];
      e0 += redS[ww][3]; e1 += redS[ww][4]; e2 += redS[ww][5];
    }
    QS[0] = q1; QS[1] = q2; QS[2] = q3;
    xB[i * 3 + 0] = xi0 + e0; xB[i * 3 + 1] = xi1 + e1; xB[i * 3 + 2] = xi2 + e2;
  }
  __syncthreads();

  // ---- node0 tail (threads 0..63) ----
  if (tid < 64) {
    const int f = tid;
    float4 a = *(const float4*)&acS[f * 4];
    float s = 1023.0f * a.x;
    s = fmaf(a.y, QS[0], s);
    s = fmaf(a.z, QS[1], s);
    s = fmaf(a.w, QS[2], s);
    sS[f] = s;
  }
  __syncthreads();
  if (tid < 64) {
    const int f = tid;
    float m = 1023.0f * eb2[f];
    #pragma unroll 4
    for (int k = 0; k < FF; ++k) m = fmaf(sS[k], ew2[k * FF + f], m);
    mS[f] = m;
  }
  __syncthreads();
  if (tid < 64) {
    const int f = tid;
    float z = nb1[f];
    #pragma unroll 4
    for (int k = 0; k < FF; ++k) z += nw1[k * FF + f];            // h == 1 part
    #pragma unroll 4
    for (int k = 0; k < FF; ++k) z = fmaf(mS[k], nw1[(FF + k) * FF + f], z);
    hidS[f] = silu_exact(z);
  }
  __syncthreads();
  if (tid < 64) {
    const int f = tid;
    float o = nb2[f] + 1.0f;
    #pragma unroll 4
    for (int k = 0; k < FF; ++k) o = fmaf(hidS[k], nw2[k * FF + f], o);
    h1[i * FF + f] = o;
  }
}

// =================== B: depth-1 prep (256 blocks x 256; 1 node per wave) ===================
__global__ __launch_bounds__(256) void k_prep1(const float* __restrict__ h1,
                                               const float* __restrict__ ew1,   // d1 (129,64)
                                               const float* __restrict__ eb1,
                                               const float* __restrict__ ccD1,  // 65
                                               float* __restrict__ HiE,
                                               float* __restrict__ Hj,
                                               float* __restrict__ P,     // (N,4)
                                               float* __restrict__ U,
                                               float* __restrict__ V,
                                               float* __restrict__ aux) { // 128: Hm,b0
  __shared__ float4 partS4[64];
  __shared__ float hmeanS[FF];
  __shared__ float HmS[FF], b0S[FF], b1S[FF];
  __shared__ float hs[4][FF];

  const int tid = threadIdx.x;
  const int lane = tid & 63;
  const int w = tid >> 6;
  const int v = blockIdx.x * 4 + w;    // this wave's node

  // ---- phase 1: mean(h1), fully coalesced float4 ----
  float4 acc = make_float4(0.f, 0.f, 0.f, 0.f);
  const float4* h1f4 = (const float4*)h1;
  #pragma unroll 8
  for (int t = 0; t < 64; ++t) {
    float4 q = h1f4[t * 256 + tid];      // k-range = 4*(tid&15) .. +3
    acc.x += q.x; acc.y += q.y; acc.z += q.z; acc.w += q.w;
  }
  #pragma unroll
  for (int m = 16; m < 64; m <<= 1) {
    acc.x += __shfl_xor(acc.x, m);
    acc.y += __shfl_xor(acc.y, m);
    acc.z += __shfl_xor(acc.z, m);
    acc.w += __shfl_xor(acc.w, m);
  }
  if (lane < 16) partS4[w * 16 + lane] = acc;
  hs[w][lane] = h1[v * FF + lane];       // stage this wave's h1 row
  __syncthreads();
  if (tid < 16) {
    float4 a = partS4[tid], b = partS4[16 + tid], c = partS4[32 + tid], d = partS4[48 + tid];
    const float inv = 1.0f / 1024.0f;
    hmeanS[4 * tid + 0] = (a.x + b.x + c.x + d.x) * inv;
    hmeanS[4 * tid + 1] = (a.y + b.y + c.y + d.y) * inv;
    hmeanS[4 * tid + 2] = (a.z + b.z + c.z + d.z) * inv;
    hmeanS[4 * tid + 3] = (a.w + b.w + c.w + d.w) * inv;
  }
  __syncthreads();

  // ---- phase 2: per-node HiE/Hj matvec (all waves); wave0 adds b-fit ----
  float a = eb1[lane], b = 0.f;
  #pragma unroll 8
  for (int m = 0; m < FF; ++m) {
    float hv = hs[w][m];
    a = fmaf(hv, ew1[m * FF + lane], a);
    b = fmaf(hv, ew1[(FF + m) * FF + lane], b);
  }
  HiE[v * FF + lane] = a;
  Hj[v * FF + lane] = b;

  if (w == 0) {
    const int k = lane;
    float Hm = 0.f, HiEm = eb1[k];
    #pragma unroll 4
    for (int m = 0; m < FF; ++m) {
      float hv = hmeanS[m];
      HiEm = fmaf(hv, ew1[m * FF + k], HiEm);
      Hm = fmaf(hv, ew1[(FF + m) * FF + k], Hm);
    }
    HmS[k] = Hm;
    const float cbar = HiEm + Hm;
    const float wk = ew1[128 * FF + k];
    float sp_lo = silu_deriv(fmaf(0.4f, wk, cbar));
    float sp_hi = silu_deriv(fmaf(1.3f, wk, cbar));
    float b1 = (sp_hi - sp_lo) * (1.0f / 0.9f);
    b0S[k] = fmaf(-0.4f, b1, sp_lo);
    b1S[k] = b1;
  }
  __syncthreads();

  // ---- phase 3: acoef + wreds -> P/U/V ----
  const float Hm = HmS[lane];
  const float cc = ccD1[lane];
  const float W0 = ccD1[FF];
  const float wk = ew1[128 * FF + lane];
  float4 ac = acoef(a + Hm, wk);
  float delta = b - Hm;
  float P0 = wred(cc * ac.x);
  float P1 = wred(cc * ac.y);
  float P2 = wred(cc * ac.z);
  float P3 = wred(cc * ac.w);
  float Uv = wred(cc * b0S[lane] * delta);
  float Vv = wred(cc * b1S[lane] * delta);
  if (lane == 0) {
    *(float4*)&P[v * 4] = make_float4(P0 + W0, P1, P2, P3);
    U[v] = Uv;
    V[v] = Vv;
  }
  if (blockIdx.x == 0 && tid < 64) {
    aux[tid] = HmS[tid];
    aux[64 + tid] = b0S[tid];
  }
}

// =================== C: pair1 + node1 + final ===================
__global__ __launch_bounds__(256) void k_d1(const float* __restrict__ xB,
                                            const float* __restrict__ h1,
                                            const float* __restrict__ HiE,
                                            const float* __restrict__ Hj,
                                            const float* __restrict__ P,
                                            const float* __restrict__ U,
                                            const float* __restrict__ V,
                                            const float* __restrict__ aux,
                                            const float* __restrict__ ew1,   // d1 (for w1r)
                                            const float* __restrict__ ew2,
                                            const float* __restrict__ eb2,
                                            const float* __restrict__ nw1,
                                            const float* __restrict__ nb1,
                                            const float* __restrict__ nw2,
                                            const float* __restrict__ nb2,
                                            const float* __restrict__ fw,    // (64,3)
                                            float* __restrict__ out) {
  __shared__ float redS[4][8];
  __shared__ float QS[3], X2S[3];
  __shared__ float sS[FF], mS[FF], hidS[FF], hvS[FF];

  const int i = blockIdx.x;
  const int tid = threadIdx.x;
  const int lane = tid & 63;
  const int w = tid >> 6;

  const float4 P4 = *(const float4*)&P[i * 4];
  const float xi0 = xB[i * 3 + 0], xi1 = xB[i * 3 + 1], xi2 = xB[i * 3 + 2];

  float Q1 = 0.f, Q2 = 0.f, Q3 = 0.f, dx0 = 0.f, dx1 = 0.f, dx2 = 0.f;
  #pragma unroll
  for (int t = 0; t < 4; ++t) {
    const int j = t * 256 + tid;
    float r, p0, p1, p2, swc;
    pair_geom(xi0, xi1, xi2, xB, j, i, r, p0, p1, p2, swc);
    float u = r * INV_RA;
    float u2 = u * u;
    Q1 += u; Q2 += u2; Q3 += u2 * u;
    float wj = fmaf(fmaf(fmaf(P4.w, u, P4.z), u, P4.y), u, P4.x);
    wj += fmaf(r, V[j], U[j]);
    float wv = wj * swc;
    dx0 = fmaf(wv, p0, dx0);
    dx1 = fmaf(wv, p1, dx1);
    dx2 = fmaf(wv, p2, dx2);
  }
  Q1 = wred(Q1); Q2 = wred(Q2); Q3 = wred(Q3);
  dx0 = wred(dx0); dx1 = wred(dx1); dx2 = wred(dx2);
  if (lane == 0) {
    redS[w][0] = Q1; redS[w][1] = Q2; redS[w][2] = Q3;
    redS[w][3] = dx0; redS[w][4] = dx1; redS[w][5] = dx2;
  }
  __syncthreads();
  if (tid == 0) {
    float q1 = 0, q2 = 0, q3 = 0, e0 = 0, e1 = 0, e2 = 0;
    #pragma unroll
    for (int ww = 0; ww < 4; ++ww) {
      q1 += redS[ww][0]; q2 += redS[ww][1]; q3 += redS[ww][2];
      e0 += redS[ww][3]; e1 += redS[ww][4]; e2 += redS[ww][5];
    }
    QS[0] = q1; QS[1] = q2; QS[2] = q3;
    X2S[0] = xi0 + e0; X2S[1] = xi1 + e1; X2S[2] = xi2 + e2;
  }
  __syncthreads();

  // ---- node1 tail ----
  if (tid < 64) {
    const int f = tid;
    const float Hm = aux[f], b0 = aux[64 + f];
    const float wk = ew1[128 * FF + f];
    float4 a = acoef(HiE[i * FF + f] + Hm, wk);
    float delta = Hj[i * FF + f] - Hm;
    float s = 1023.0f * a.x;
    s = fmaf(a.y, QS[0], s);
    s = fmaf(a.z, QS[1], s);
    s = fmaf(a.w, QS[2], s);
    s = fmaf(-b0, delta, s);
    sS[f] = s;
    hvS[f] = h1[i * FF + f];
  }
  __syncthreads();
  if (tid < 64) {
    const int f = tid;
    float m = 1023.0f * eb2[f];
    #pragma unroll 4
    for (int k = 0; k < FF; ++k) m = fmaf(sS[k], ew2[k * FF + f], m);
    mS[f] = m;
  }
  __syncthreads();
  if (tid < 64) {
    const int f = tid;
    float z = nb1[f];
    #pragma unroll 4
    for (int k = 0; k < FF; ++k) z = fmaf(hvS[k], nw1[k * FF + f], z);
    #pragma unroll 4
    for (int k = 0; k < FF; ++k) z = fmaf(mS[k], nw1[(FF + k) * FF + f], z);
    hidS[f] = silu_exact(z);
  }
  __syncthreads();
  if (tid < 64) {
    const int f = tid;
    float o = nb2[f] + hvS[f];
    #pragma unroll 4
    for (int k = 0; k < FF; ++k) o = fmaf(hidS[k], nw2[k * FF + f], o);
    float p0 = wred(o * fw[f * 3 + 0]);
    float p1 = wred(o * fw[f * 3 + 1]);
    float p2 = wred(o * fw[f * 3 + 2]);
    if (f == 0) {
      out[i * 3 + 0] = p0 + X2S[0];
      out[i * 3 + 1] = p1 + X2S[1];
      out[i * 3 + 2] = p2 + X2S[2];
    }
  }
}

extern "C" void kernel_launch(void* const* d_in, const int* in_sizes, int n_in,
                              void* d_out, int out_size, void* d_ws, size_t ws_size,
                              hipStream_t stream) {
  const float* x_in = (const float*)d_in[0];
  const float* ew1  = (const float*)d_in[1];   // (2,129,64)
  const float* eb1  = (const float*)d_in[2];   // (2,64)
  const float* ew2  = (const float*)d_in[3];   // (2,64,64)
  const float* eb2  = (const float*)d_in[4];   // (2,64)
  const float* cw1  = (const float*)d_in[5];   // (2,64,64)
  const float* cb1  = (const float*)d_in[6];   // (2,64)
  const float* cw2  = (const float*)d_in[7];   // (2,64,1)
  const float* cb2  = (const float*)d_in[8];   // (2,1)
  const float* nw1  = (const float*)d_in[9];   // (2,128,64)
  const float* nb1  = (const float*)d_in[10];  // (2,64)
  const float* nw2  = (const float*)d_in[11];  // (2,64,64)
  const float* nb2  = (const float*)d_in[12];  // (2,64)
  const float* fw   = (const float*)d_in[13];  // (64,3)
  float* out = (float*)d_out;

  float* ws = (float*)d_ws;
  float* xB   = ws;               // 3072
  float* h1   = xB + 3072;        // 65536
  float* HiE  = h1 + 65536;       // 65536
  float* Hj   = HiE + 65536;      // 65536
  float* P    = Hj + 65536;       // 4096
  float* U    = P + 4096;         // 1024
  float* V    = U + 1024;         // 1024
  float* aux  = V + 1024;         // 128
  float* ccD1 = aux + 128;        // 128 (65 used)

  const float* ew1d1 = ew1 + 129 * FF;

  k_d0<<<NN, 256, 0, stream>>>(x_in, ew1, ew2, cw1, eb1, eb2, cb1, cw2, cb2,
                               nw1, nb1, nw2, nb2,
                               cw1 + 4096, ew2 + 4096, eb2 + FF, cb1 + FF, cw2 + FF, cb2 + 1,
                               xB, h1, ccD1);
  k_prep1<<<256, 256, 0, stream>>>(h1, ew1d1, eb1 + FF, ccD1, HiE, Hj, P, U, V, aux);
  k_d1<<<NN, 256, 0, stream>>>(xB, h1, HiE, Hj, P, U, V, aux,
                               ew1d1, ew2 + 4096, eb2 + FF,
                               nw1 + 128 * FF, nb1 + FF, nw2 + 4096, nb2 + FF,
                               fw, out);
}